// Round 3
// baseline (41.480 us; speedup 1.0000x reference)
//
#include <hip/hip_runtime.h>
#include <cstdint>

typedef unsigned short u16;
typedef unsigned int u32;

constexpr int BB = 16, HH = 512, WW = 512;
constexpr int NPIX = BB * HH * WW;          // 4,194,304

// workspace layout (bytes)
constexpr size_t D1_OFF   = 0;                    // s16 combined d1p-d1n, 8 MiB
constexpr size_t PART_OFF = (size_t)NPIX * 2;

// envelope tiling
constexpr int RMAX  = 32;                 // max |dy| searched (data max ~15)
constexpr int XT    = 64;                 // output rows per block
constexpr int TROWS = XT + 2 * RMAX;      // 128 tile rows
constexpr int CSTR  = TROWS / 2 + 1;      // 65 dwords per padded LDS column
constexpr int DYS   = 12;                 // static register-window radius

// ---------------- Kernel A: per-row 1D distances (single boundary scan) ------
// d1 = distance to nearest opposite-value pixel in the row = distance to the
// nearest run boundary. Left identity -2048 / right identity 2559 reproduce
// the reference's big=2048 scan values exactly. v = t ? +d1 : -d1 (s16).
__global__ void __launch_bounds__(256) k_rows(const int* __restrict__ tg,
                                              short* __restrict__ d1c) {
  const int lane = threadIdx.x & 63;
  const int wv   = threadIdx.x >> 6;
  const int row  = blockIdx.x * 4 + wv;        // b*512 + h, 8192 rows
  const int c0   = lane * 8;
  const int* rp  = tg + (size_t)row * WW;
  int4 va = *(const int4*)(rp + c0);
  int4 vb = *(const int4*)(rp + c0 + 4);
  int t[8] = {va.x, va.y, va.z, va.w, vb.x, vb.y, vb.z, vb.w};
  int tprev0 = __shfl_up(t[7], 1);   // lane0 value unused (i==0 case)
  int tnext7 = __shfl_down(t[0], 1); // lane63 value unused (i==511 case)

  // left boundary positions, inclusive prefix max
  int lm[8]; int m = -2048;
  #pragma unroll
  for (int k = 0; k < 8; ++k) {
    int i = c0 + k;
    int tp = (k == 0) ? tprev0 : t[k - 1];
    int c = (i > 0 && t[k] != tp) ? i : -2048;
    m = max(m, c); lm[k] = m;
  }
  int X = m;
  #pragma unroll
  for (int off = 1; off < 64; off <<= 1) {
    int y = __shfl_up(X, off);
    if (lane >= off) X = max(X, y);
  }
  int E = __shfl_up(X, 1); if (lane == 0) E = -2048;

  // right boundary positions, inclusive suffix min
  int sm[8]; m = 2559;
  #pragma unroll
  for (int k = 7; k >= 0; --k) {
    int i = c0 + k;
    int tn = (k == 7) ? tnext7 : t[k + 1];
    int c = (i < 511 && t[k] != tn) ? i : 2559;
    m = min(m, c); sm[k] = m;
  }
  int X2 = m;
  #pragma unroll
  for (int off = 1; off < 64; off <<= 1) {
    int y = __shfl_down(X2, off);
    if (lane + off < 64) X2 = min(X2, y);
  }
  int E2 = __shfl_down(X2, 1); if (lane == 63) E2 = 2559;

  u32 r[8];
  #pragma unroll
  for (int k = 0; k < 8; ++k) {
    int i = c0 + k;
    int L = max(lm[k], E), R = min(sm[k], E2);
    int d1 = min(i - L + 1, R - i + 1);
    int v = t[k] ? d1 : -d1;
    r[k] = (u32)(u16)(short)v;
  }
  uint4 o;
  o.x = r[0] | (r[1] << 16);
  o.y = r[2] | (r[3] << 16);
  o.z = r[4] | (r[5] << 16);
  o.w = r[6] | (r[7] << 16);
  ((uint4*)d1c)[(size_t)row * (WW / 8) + lane] = o;
}

// ------------- Kernel B: column lower-envelope + all reductions --------------
__global__ void __launch_bounds__(256) k_env(const short* __restrict__ d1c,
                                             const float* __restrict__ inp,
                                             float* __restrict__ partS,
                                             u32* __restrict__ partM,
                                             float* __restrict__ partP,
                                             float* __restrict__ partTP,
                                             int* __restrict__ partT) {
  __shared__ u32 tileT[64 * CSTR];             // column-major, 2 rows per dword
  const int tid = threadIdx.x;
  const int cg = blockIdx.x, xt = blockIdx.y, b = blockIdx.z;
  const int w0 = cg * 64, x0 = xt * XT;

  // transposed staging: 512 units = (row-pair r2 0..63) x (col-group cg8 0..7)
  #pragma unroll
  for (int u = 0; u < 2; ++u) {
    int idx = tid + u * 256;
    int r2 = idx >> 3, cg8 = idx & 7;
    int g0 = x0 - RMAX + 2 * r2;               // global image row (even of pair)
    uint4 a = make_uint4(0, 0, 0, 0), b4 = make_uint4(0, 0, 0, 0);
    const short* base = d1c + ((size_t)b * HH) * WW + w0 + cg8 * 8;
    if ((unsigned)g0 < (unsigned)HH)       a  = *(const uint4*)(base + (size_t)g0 * WW);
    if ((unsigned)(g0 + 1) < (unsigned)HH) b4 = *(const uint4*)(base + (size_t)(g0 + 1) * WW);
    u32 al[8] = {a.x & 0xffffu, a.x >> 16, a.y & 0xffffu, a.y >> 16,
                 a.z & 0xffffu, a.z >> 16, a.w & 0xffffu, a.w >> 16};
    u32 bl[8] = {b4.x & 0xffffu, b4.x >> 16, b4.y & 0xffffu, b4.y >> 16,
                 b4.z & 0xffffu, b4.z >> 16, b4.w & 0xffffu, b4.w >> 16};
    #pragma unroll
    for (int j = 0; j < 8; ++j)
      tileT[(cg8 * 8 + j) * CSTR + r2] = al[j] | (bl[j] << 16);
  }
  __syncthreads();

  const int wv = tid >> 6, lane = tid & 63;
  const int r0 = RMAX + wv * 16;               // first own tile row (even)
  const u32* colp = tileT + lane * CSTR;

  // static register window: tile rows [r0-DYS, r0+15+DYS] = 40 shorts, 20 dwords
  int win[20];
  const int wb = (r0 - DYS) >> 1;              // even short base -> dword base
  #pragma unroll
  for (int j = 0; j < 20; ++j) win[j] = (int)colp[wb + j];
  auto GETS = [&](int i) -> int {              // short i of window, static i
    return (int)(short)(win[i >> 1] >> ((i & 1) * 16));
  };

  // own distances + hoisted wave max
  int uo[16]; int um = 1;
  #pragma unroll
  for (int k = 0; k < 16; ++k) {
    int v = GETS(k + DYS);
    int u = v > 0 ? v : -v;
    uo[k] = u; um = max(um, u);
  }
  #pragma unroll
  for (int off = 32; off >= 1; off >>= 1) um = max(um, __shfl_xor(um, off));
  const int Rw = min(um - 1, DYS);             // winner needs dy < own d1
  const bool deep = (um - 1 > DYS);            // rare fallback (wave-uniform)

  float aP = 0.f, aTP = 0.f, aS = 0.f;
  u32 aM = 0; int aC = 0;

  #pragma unroll
  for (int k = 0; k < 16; ++k) {
    const int x = x0 + wv * 16 + k;            // global row, wave-uniform
    const int dU = min(Rw, x), dD = min(Rw, 511 - x);
    int v0 = GETS(k + DYS);
    bool fg = v0 > 0;
    u32 best = (u32)(uo[k] * uo[k]);
    #pragma unroll
    for (int dy = 1; dy <= DYS; ++dy) {
      if (dy > dD && dy > dU) break;           // wave-uniform early exit
      if (dy <= dD) {
        int v = GETS(k + DYS + dy);
        int u = fg ? v : -v; u = max(u, 0);
        best = min(best, (u32)(u * u + dy * dy));
      }
      if (dy <= dU) {
        int v = GETS(k + DYS - dy);
        int u = fg ? v : -v; u = max(u, 0);
        best = min(best, (u32)(u * u + dy * dy));
      }
    }
    if (deep) {                                // exact up to RMAX, ~never taken
      int RwF = min(um - 1, RMAX);
      int fD = min(RwF, 511 - x), fU = min(RwF, x);
      for (int dy = DYS + 1; dy <= fD; ++dy) {
        int rr = r0 + k + dy;
        int v = (int)(short)(colp[rr >> 1] >> ((rr & 1) * 16));
        int u = fg ? v : -v; u = max(u, 0);
        best = min(best, (u32)(u * u + dy * dy));
      }
      for (int dy = DYS + 1; dy <= fU; ++dy) {
        int rr = r0 + k - dy;
        int v = (int)(short)(colp[rr >> 1] >> ((rr & 1) * 16));
        int u = fg ? v : -v; u = max(u, 0);
        best = min(best, (u32)(u * u + dy * dy));
      }
    }

    float D = sqrtf((float)best);              // = posdis+negdis at this pixel
    float vv = inp[((size_t)(b * HH + x)) * WW + w0 + lane];
    float p = 1.0f / (1.0f + __expf(-vv));
    aP += p;
    if (fg) { aTP += p; aC += 1; aS -= p * D; } else { aS += p * D; }
    aM = max(aM, best);
  }

  // wave reduce
  #pragma unroll
  for (int off = 32; off >= 1; off >>= 1) {
    aP  += __shfl_xor(aP, off);
    aTP += __shfl_xor(aTP, off);
    aS  += __shfl_xor(aS, off);
    aC  += __shfl_xor(aC, off);
    aM = max(aM, (u32)__shfl_xor((int)aM, off));
  }
  __shared__ float rP[4], rTP[4], rS[4];
  __shared__ u32 rM[4]; __shared__ int rC[4];
  if (lane == 0) { rP[wv] = aP; rTP[wv] = aTP; rS[wv] = aS; rM[wv] = aM; rC[wv] = aC; }
  __syncthreads();
  if (tid == 0) {
    int part = (b * 8 + xt) * 8 + cg;
    partP[part]  = rP[0] + rP[1] + rP[2] + rP[3];
    partTP[part] = rTP[0] + rTP[1] + rTP[2] + rTP[3];
    partS[part]  = rS[0] + rS[1] + rS[2] + rS[3];
    partM[part]  = max(max(rM[0], rM[1]), max(rM[2], rM[3]));
    partT[part]  = rC[0] + rC[1] + rC[2] + rC[3];
  }
}

// ---------------- Kernel C: finalize scalar loss -----------------------------
__global__ void __launch_bounds__(256) k_final(const float* __restrict__ partS,
                                               const u32* __restrict__ partM,
                                               const float* __restrict__ partP,
                                               const float* __restrict__ partTP,
                                               const int* __restrict__ partT,
                                               float* __restrict__ out) {
  const int t = threadIdx.x;
  const int img = t >> 4, j = t & 15;          // 16 threads per image
  float s = 0.f, p = 0.f, tp = 0.f; int tc = 0; u32 m2 = 0;
  #pragma unroll
  for (int q = 0; q < 4; ++q) {
    int e = img * 64 + j + q * 16;
    s += partS[e]; p += partP[e]; tp += partTP[e]; tc += partT[e];
    m2 = max(m2, partM[e]);
  }
  #pragma unroll
  for (int off = 8; off >= 1; off >>= 1) {
    s  += __shfl_xor(s, off);
    p  += __shfl_xor(p, off);
    tp += __shfl_xor(tp, off);
    tc += __shfl_xor(tc, off);
    m2 = max(m2, (u32)__shfl_xor((int)m2, off));
  }
  __shared__ float shC[16], shP[16], shTP[16]; __shared__ int shT[16];
  if (j == 0) {
    float bmax = sqrtf((float)m2);
    shC[img] = (tc > 0) ? (s / (bmax + 1e-8f)) : 0.0f;   // anypos guard
    shP[img] = p; shTP[img] = tp; shT[img] = tc;
  }
  __syncthreads();
  if (t == 0) {
    float sumP = 0.f, TP = 0.f, sumT = 0.f, bl = 0.f;
    for (int i = 0; i < 16; ++i) { sumP += shP[i]; TP += shTP[i]; sumT += (float)shT[i]; bl += shC[i]; }
    float FP = sumP - TP, FN = sumT - TP;
    float tv = (TP + 1.0f) / (TP + 0.3f * FP + 0.7f * FN + 1.0f);
    float ft = powf(1.0f - tv, 1.33f);
    float dice = (2.0f * TP + 1.0f) / (sumP + sumT + 1.0f);
    float dl = 1.0f - dice;
    float blm = bl / (float)NPIX;
    if (isnan(ft)) ft = 0.0f;
    if (isnan(dl)) dl = 0.0f;
    if (isnan(blm)) blm = 0.0f;
    out[0] = 0.5f * ft + 0.3f * dl + 0.2f * blm;
  }
}

extern "C" void kernel_launch(void* const* d_in, const int* in_sizes, int n_in,
                              void* d_out, int out_size, void* d_ws, size_t ws_size,
                              hipStream_t stream) {
  const float* inp = (const float*)d_in[0];
  const int* tg = (const int*)d_in[1];
  float* out = (float*)d_out;
  char* ws = (char*)d_ws;
  short* d1c = (short*)(ws + D1_OFF);
  float* partS  = (float*)(ws + PART_OFF);
  u32*   partM  = (u32*)(ws + PART_OFF + 4096);
  float* partP  = (float*)(ws + PART_OFF + 8192);
  float* partTP = (float*)(ws + PART_OFF + 12288);
  int*   partT  = (int*)(ws + PART_OFF + 16384);

  hipLaunchKernelGGL(k_rows, dim3(BB * HH / 4), dim3(256), 0, stream, tg, d1c);
  hipLaunchKernelGGL(k_env, dim3(WW / 64, HH / XT, BB), dim3(256), 0, stream,
                     d1c, inp, partS, partM, partP, partTP, partT);
  hipLaunchKernelGGL(k_final, dim3(1), dim3(256), 0, stream,
                     partS, partM, partP, partTP, partT, out);
}

// Round 4
// 30.602 us; speedup vs baseline: 1.3555x; 1.3555x over previous
//
#include <hip/hip_runtime.h>
#include <cstdint>

typedef unsigned short u16;
typedef unsigned int u32;

constexpr int BB = 16, HH = 512, WW = 512;
constexpr int NPIX = BB * HH * WW;          // 4,194,304

// workspace layout (bytes)
constexpr size_t D1_OFF   = 0;                    // s16 combined d1p-d1n, 8 MiB
constexpr size_t PART_OFF = (size_t)NPIX * 2;

// envelope tiling
constexpr int HALO  = 32;                 // vertical halo (deep search cap)
constexpr int XT    = 64;                 // output rows per block
constexpr int TROWS = XT + 2 * HALO;      // 128 tile rows
constexpr int CDW   = TROWS / 2 + 1;      // 65 dwords per padded LDS column

// ---------------- Kernel A: per-row 1D distances (single boundary scan) ------
// d1 = distance to nearest opposite-value pixel in the row (= distance to the
// nearest run boundary). Left identity -2048 / right identity 2559 reproduce
// the reference's big=2048 scan values exactly. v = t ? +d1 : -d1 (s16).
__global__ void __launch_bounds__(256) k_rows(const int* __restrict__ tg,
                                              short* __restrict__ d1c) {
  const int lane = threadIdx.x & 63;
  const int wv   = threadIdx.x >> 6;
  const int row  = blockIdx.x * 4 + wv;        // b*512 + h, 8192 rows
  const int c0   = lane * 8;
  const int* rp  = tg + (size_t)row * WW;
  int4 va = *(const int4*)(rp + c0);
  int4 vb = *(const int4*)(rp + c0 + 4);
  int t[8] = {va.x, va.y, va.z, va.w, vb.x, vb.y, vb.z, vb.w};
  int tprev0 = __shfl_up(t[7], 1);   // lane0 value unused (i==0 case)
  int tnext7 = __shfl_down(t[0], 1); // lane63 value unused (i==511 case)

  // left boundary positions, inclusive prefix max
  int lm[8]; int m = -2048;
  #pragma unroll
  for (int k = 0; k < 8; ++k) {
    int i = c0 + k;
    int tp = (k == 0) ? tprev0 : t[k - 1];
    int c = (i > 0 && t[k] != tp) ? i : -2048;
    m = max(m, c); lm[k] = m;
  }
  int X = m;
  #pragma unroll
  for (int off = 1; off < 64; off <<= 1) {
    int y = __shfl_up(X, off);
    if (lane >= off) X = max(X, y);
  }
  int E = __shfl_up(X, 1); if (lane == 0) E = -2048;

  // right boundary positions, inclusive suffix min
  int sm[8]; m = 2559;
  #pragma unroll
  for (int k = 7; k >= 0; --k) {
    int i = c0 + k;
    int tn = (k == 7) ? tnext7 : t[k + 1];
    int c = (i < 511 && t[k] != tn) ? i : 2559;
    m = min(m, c); sm[k] = m;
  }
  int X2 = m;
  #pragma unroll
  for (int off = 1; off < 64; off <<= 1) {
    int y = __shfl_down(X2, off);
    if (lane + off < 64) X2 = min(X2, y);
  }
  int E2 = __shfl_down(X2, 1); if (lane == 63) E2 = 2559;

  u32 r[8];
  #pragma unroll
  for (int k = 0; k < 8; ++k) {
    int i = c0 + k;
    int L = max(lm[k], E), R = min(sm[k], E2);
    int d1 = min(i - L + 1, R - i + 1);
    int v = t[k] ? d1 : -d1;
    r[k] = (u32)(u16)(short)v;
  }
  uint4 o;
  o.x = r[0] | (r[1] << 16);
  o.y = r[2] | (r[3] << 16);
  o.z = r[4] | (r[5] << 16);
  o.w = r[6] | (r[7] << 16);
  ((uint4*)d1c)[(size_t)row * (WW / 8) + lane] = o;
}

// ------------- Kernel B: column lower-envelope + all reductions --------------
// Per-row body, parity P = (tile row c) & 1 (compile-time). Window of 8
// consecutive dwords covers dy >= 1..7 both sides (plus harmless dy=0/8
// extras); dy^2 are static immediates. Sentinel 3000 pads OOB rows, so no
// image-boundary clamping anywhere.
template <int P>
__device__ __forceinline__ void row_body(
    int c, const u32* __restrict__ pc, const u32* __restrict__ nc,
    const float* __restrict__ ip,
    float& aP, float& aTP, float& aS, u32& aM, int& aC) {
  constexpr int LOT[2][8] = {{64, 36, 16, 4, 0, 4, 16, 36},
                             {49, 25,  9, 1, 1, 9, 25, 49}};
  constexpr int HIT[2][8] = {{49, 25,  9, 1, 1, 9, 25, 49},
                             {36, 16,  4, 0, 4, 16, 36, 64}};
  const int e = c >> 1;
  const u32 vpd = pc[e], vnd = nc[e];
  const int vp = (int)((vpd >> (16 * P)) & 0xffffu);
  const int vn = (int)((vnd >> (16 * P)) & 0xffffu);
  const bool fg = vp > 0;
  const int uo = max(vp, vn);                  // own-class 1D distance
  const u32* cb = fg ? pc : nc;                // search own-class tile
  u32 best = (u32)(uo * uo);
  const int s = e + P - 4;                     // window dwords s..s+7
  #pragma unroll
  for (int i = 0; i < 8; ++i) {
    u32 d = cb[s + i];
    int lo = (int)(d & 0xffffu), hi = (int)(d >> 16);
    best = min(best, (u32)(lo * lo + LOT[P][i]));
    best = min(best, (u32)(hi * hi + HIT[P][i]));
  }
  if (__any(uo > 8)) {                         // rare exact fallback, dy 8..32
    #pragma unroll 1
    for (int dy = 8; dy <= HALO; ++dy) {
      int rd = c + dy, ru = c - dy;
      u32 dd = cb[rd >> 1], du = cb[ru >> 1];
      int ud = (int)((dd >> ((rd & 1) * 16)) & 0xffffu);
      int uu = (int)((du >> ((ru & 1) * 16)) & 0xffffu);
      int q = dy * dy;
      best = min(best, (u32)(ud * ud + q));
      best = min(best, (u32)(uu * uu + q));
    }
  }
  float D = sqrtf((float)best);                // = posdis+negdis at this pixel
  float v = *ip;
  float p = 1.0f / (1.0f + __expf(-v));
  aP += p;
  if (fg) { aTP += p; aC += 1; aS -= p * D; } else { aS += p * D; }
  aM = max(aM, best);
}

__global__ void __launch_bounds__(256) k_env(const short* __restrict__ d1c,
                                             const float* __restrict__ inp,
                                             float* __restrict__ partS,
                                             u32* __restrict__ partM,
                                             float* __restrict__ partP,
                                             float* __restrict__ partTP,
                                             int* __restrict__ partT) {
  __shared__ u32 posT[64 * CDW];               // column-major, 2 rows per dword
  __shared__ u32 negT[64 * CDW];
  const int tid = threadIdx.x;
  const int cg = blockIdx.x, xt = blockIdx.y, b = blockIdx.z;
  const int w0 = cg * 64, x0 = xt * XT;

  // transposed two-class staging: 512 units = (row-pair r2) x (col-group c8)
  #pragma unroll
  for (int u = 0; u < 2; ++u) {
    int idx = tid + u * 256;
    int r2 = idx >> 3, c8 = idx & 7;
    int g0 = x0 - HALO + 2 * r2;
    const short* base = d1c + ((size_t)(b * HH)) * WW + w0 + c8 * 8;
    uint4 A = make_uint4(0, 0, 0, 0), Bv = make_uint4(0, 0, 0, 0);
    bool ok0 = (unsigned)g0 < (unsigned)HH;
    bool ok1 = (unsigned)(g0 + 1) < (unsigned)HH;
    if (ok0) A  = *(const uint4*)(base + (size_t)g0 * WW);
    if (ok1) Bv = *(const uint4*)(base + (size_t)(g0 + 1) * WW);
    u32 aw[4] = {A.x, A.y, A.z, A.w}, bw[4] = {Bv.x, Bv.y, Bv.z, Bv.w};
    #pragma unroll
    for (int j = 0; j < 8; ++j) {
      int sa = (int)(short)(aw[j >> 1] >> ((j & 1) * 16));
      int sb = (int)(short)(bw[j >> 1] >> ((j & 1) * 16));
      int vpa = ok0 ? max(sa, 0) : 3000, vna = ok0 ? max(-sa, 0) : 3000;
      int vpb = ok1 ? max(sb, 0) : 3000, vnb = ok1 ? max(-sb, 0) : 3000;
      int col = c8 * 8 + j;
      posT[col * CDW + r2] = (u32)vpa | ((u32)vpb << 16);
      negT[col * CDW + r2] = (u32)vna | ((u32)vnb << 16);
    }
  }
  __syncthreads();

  const int wv = tid >> 6, lane = tid & 63;
  const u32* pc = posT + lane * CDW;
  const u32* nc = negT + lane * CDW;
  const float* ip0 = inp + ((size_t)(b * HH + x0 + wv * 16)) * WW + w0 + lane;
  float aP = 0.f, aTP = 0.f, aS = 0.f;
  u32 aM = 0; int aC = 0;

  #pragma unroll 1
  for (int k2 = 0; k2 < 8; ++k2) {
    const int c = HALO + wv * 16 + 2 * k2;
    row_body<0>(c,     pc, nc, ip0 + (size_t)(2 * k2) * WW,     aP, aTP, aS, aM, aC);
    row_body<1>(c + 1, pc, nc, ip0 + (size_t)(2 * k2 + 1) * WW, aP, aTP, aS, aM, aC);
  }

  // wave reduce
  #pragma unroll
  for (int off = 32; off >= 1; off >>= 1) {
    aP  += __shfl_xor(aP, off);
    aTP += __shfl_xor(aTP, off);
    aS  += __shfl_xor(aS, off);
    aC  += __shfl_xor(aC, off);
    aM = max(aM, (u32)__shfl_xor((int)aM, off));
  }
  __shared__ float rP[4], rTP[4], rS[4];
  __shared__ u32 rM[4]; __shared__ int rC[4];
  if (lane == 0) { rP[wv] = aP; rTP[wv] = aTP; rS[wv] = aS; rM[wv] = aM; rC[wv] = aC; }
  __syncthreads();
  if (tid == 0) {
    int part = (b * 8 + xt) * 8 + cg;
    partP[part]  = rP[0] + rP[1] + rP[2] + rP[3];
    partTP[part] = rTP[0] + rTP[1] + rTP[2] + rTP[3];
    partS[part]  = rS[0] + rS[1] + rS[2] + rS[3];
    partM[part]  = max(max(rM[0], rM[1]), max(rM[2], rM[3]));
    partT[part]  = rC[0] + rC[1] + rC[2] + rC[3];
  }
}

// ---------------- Kernel C: finalize scalar loss -----------------------------
__global__ void __launch_bounds__(256) k_final(const float* __restrict__ partS,
                                               const u32* __restrict__ partM,
                                               const float* __restrict__ partP,
                                               const float* __restrict__ partTP,
                                               const int* __restrict__ partT,
                                               float* __restrict__ out) {
  const int t = threadIdx.x;
  const int img = t >> 4, j = t & 15;          // 16 threads per image
  float s = 0.f, p = 0.f, tp = 0.f; int tc = 0; u32 m2 = 0;
  #pragma unroll
  for (int q = 0; q < 4; ++q) {
    int e = img * 64 + j + q * 16;
    s += partS[e]; p += partP[e]; tp += partTP[e]; tc += partT[e];
    m2 = max(m2, partM[e]);
  }
  #pragma unroll
  for (int off = 8; off >= 1; off >>= 1) {
    s  += __shfl_xor(s, off);
    p  += __shfl_xor(p, off);
    tp += __shfl_xor(tp, off);
    tc += __shfl_xor(tc, off);
    m2 = max(m2, (u32)__shfl_xor((int)m2, off));
  }
  __shared__ float shC[16], shP[16], shTP[16]; __shared__ int shT[16];
  if (j == 0) {
    float bmax = sqrtf((float)m2);
    shC[img] = (tc > 0) ? (s / (bmax + 1e-8f)) : 0.0f;   // anypos guard
    shP[img] = p; shTP[img] = tp; shT[img] = tc;
  }
  __syncthreads();
  if (t == 0) {
    float sumP = 0.f, TP = 0.f, sumT = 0.f, bl = 0.f;
    for (int i = 0; i < 16; ++i) { sumP += shP[i]; TP += shTP[i]; sumT += (float)shT[i]; bl += shC[i]; }
    float FP = sumP - TP, FN = sumT - TP;
    float tv = (TP + 1.0f) / (TP + 0.3f * FP + 0.7f * FN + 1.0f);
    float ft = powf(1.0f - tv, 1.33f);
    float dice = (2.0f * TP + 1.0f) / (sumP + sumT + 1.0f);
    float dl = 1.0f - dice;
    float blm = bl / (float)NPIX;
    if (isnan(ft)) ft = 0.0f;
    if (isnan(dl)) dl = 0.0f;
    if (isnan(blm)) blm = 0.0f;
    out[0] = 0.5f * ft + 0.3f * dl + 0.2f * blm;
  }
}

extern "C" void kernel_launch(void* const* d_in, const int* in_sizes, int n_in,
                              void* d_out, int out_size, void* d_ws, size_t ws_size,
                              hipStream_t stream) {
  const float* inp = (const float*)d_in[0];
  const int* tg = (const int*)d_in[1];
  float* out = (float*)d_out;
  char* ws = (char*)d_ws;
  short* d1c = (short*)(ws + D1_OFF);
  float* partS  = (float*)(ws + PART_OFF);
  u32*   partM  = (u32*)(ws + PART_OFF + 4096);
  float* partP  = (float*)(ws + PART_OFF + 8192);
  float* partTP = (float*)(ws + PART_OFF + 12288);
  int*   partT  = (int*)(ws + PART_OFF + 16384);

  hipLaunchKernelGGL(k_rows, dim3(BB * HH / 4), dim3(256), 0, stream, tg, d1c);
  hipLaunchKernelGGL(k_env, dim3(WW / 64, HH / XT, BB), dim3(256), 0, stream,
                     d1c, inp, partS, partM, partP, partTP, partT);
  hipLaunchKernelGGL(k_final, dim3(1), dim3(256), 0, stream,
                     partS, partM, partP, partTP, partT, out);
}

// Round 5
// 28.571 us; speedup vs baseline: 1.4518x; 1.0711x over previous
//
#include <hip/hip_runtime.h>
#include <cstdint>

typedef unsigned short u16;
typedef unsigned int u32;
typedef unsigned short us2 __attribute__((ext_vector_type(2)));

constexpr int BB = 16, HH = 512, WW = 512;
constexpr int NPIX = BB * HH * WW;          // 4,194,304

// workspace layout (bytes)
constexpr size_t D1_OFF   = 0;                    // s8 signed d1 (cap 127), 4 MiB
constexpr size_t PART_OFF = (size_t)NPIX;

// envelope tiling
constexpr int HALO  = 32;                 // vertical halo (deep search cap)
constexpr int XT    = 64;                 // output rows per block
constexpr int TROWS = XT + 2 * HALO;      // 128 tile rows
constexpr int CDW   = TROWS / 2 + 1;      // 65 dwords per padded LDS column

// ---------------- Kernel A: per-row 1D distances (single boundary scan) ------
// d1 = distance to nearest opposite-value pixel in the row (= distance to the
// nearest run boundary), capped at 127. v = t ? +d1 : -d1 stored as s8.
__global__ void __launch_bounds__(256) k_rows(const int* __restrict__ tg,
                                              char* __restrict__ d1b) {
  const int lane = threadIdx.x & 63;
  const int wv   = threadIdx.x >> 6;
  const int row  = blockIdx.x * 4 + wv;        // b*512 + h, 8192 rows
  const int c0   = lane * 8;
  const int* rp  = tg + (size_t)row * WW;
  int4 va = *(const int4*)(rp + c0);
  int4 vb = *(const int4*)(rp + c0 + 4);
  int t[8] = {va.x, va.y, va.z, va.w, vb.x, vb.y, vb.z, vb.w};
  int tprev0 = __shfl_up(t[7], 1);   // lane0 value unused (i==0 case)
  int tnext7 = __shfl_down(t[0], 1); // lane63 value unused (i==511 case)

  // left boundary positions, inclusive prefix max
  int lm[8]; int m = -2048;
  #pragma unroll
  for (int k = 0; k < 8; ++k) {
    int i = c0 + k;
    int tp = (k == 0) ? tprev0 : t[k - 1];
    int c = (i > 0 && t[k] != tp) ? i : -2048;
    m = max(m, c); lm[k] = m;
  }
  int X = m;
  #pragma unroll
  for (int off = 1; off < 64; off <<= 1) {
    int y = __shfl_up(X, off);
    if (lane >= off) X = max(X, y);
  }
  int E = __shfl_up(X, 1); if (lane == 0) E = -2048;

  // right boundary positions, inclusive suffix min
  int sm[8]; m = 2559;
  #pragma unroll
  for (int k = 7; k >= 0; --k) {
    int i = c0 + k;
    int tn = (k == 7) ? tnext7 : t[k + 1];
    int c = (i < 511 && t[k] != tn) ? i : 2559;
    m = min(m, c); sm[k] = m;
  }
  int X2 = m;
  #pragma unroll
  for (int off = 1; off < 64; off <<= 1) {
    int y = __shfl_down(X2, off);
    if (lane + off < 64) X2 = min(X2, y);
  }
  int E2 = __shfl_down(X2, 1); if (lane == 63) E2 = 2559;

  u32 lo = 0, hi = 0;
  #pragma unroll
  for (int k = 0; k < 8; ++k) {
    int i = c0 + k;
    int L = max(lm[k], E), R = min(sm[k], E2);
    int d1 = min(min(i - L + 1, R - i + 1), 127);
    int v = t[k] ? d1 : -d1;
    u32 b8 = (u32)(v & 0xff);
    if (k < 4) lo |= b8 << (8 * k); else hi |= b8 << (8 * (k - 4));
  }
  uint2 o = make_uint2(lo, hi);
  ((uint2*)d1b)[(size_t)row * (WW / 8) + lane] = o;
}

// ------------- Kernel B: column lower-envelope + all reductions --------------
// Per-row body, parity P = (tile row) & 1 (compile-time). Window of 8
// consecutive dwords (16 rows) covers dy 1..7 both sides; dy^2 pairs are
// compile-time packed constants; candidates evaluated with packed u16 math.
// Sentinel 127 pads OOB rows (no image-boundary clamping anywhere).
template <int P>
__device__ __forceinline__ void row_body(
    int e, const u32* __restrict__ pc, const u32* __restrict__ nc,
    const float* __restrict__ ip,
    float& aP, float& aTP, float& aS, u32& aM, int& aC) {
  constexpr u16 KL[2][8] = {{64, 36, 16, 4, 0, 4, 16, 36},
                            {49, 25,  9, 1, 1, 9, 25, 49}};
  constexpr u16 KH[2][8] = {{49, 25,  9, 1, 1, 9, 25, 49},
                            {36, 16,  4, 0, 4, 16, 36, 64}};
  const u32 pd = pc[e], nd = nc[e];
  const int vp = (P == 0) ? (int)(pd & 0xffffu) : (int)(pd >> 16);
  const int vn = (P == 0) ? (int)(nd & 0xffffu) : (int)(nd >> 16);
  const bool fg = vp > 0;
  const int uo = max(vp, vn);                  // own-class 1D distance (one is 0)
  const u32* cb = fg ? pc : nc;                // search own-class tile
  const us2* cb2 = (const us2*)cb;
  const int s = e + P - 4;                     // window dwords s..s+7
  us2 bestpk = __builtin_bit_cast(us2, 0xffffffffu);
  #pragma unroll
  for (int i = 0; i < 8; ++i) {
    us2 w = cb2[s + i];
    us2 k = __builtin_bit_cast(us2, (u32)KL[P][i] | ((u32)KH[P][i] << 16));
    us2 cnd = (us2)(w * w + k);
    bestpk = __builtin_elementwise_min(bestpk, cnd);
  }
  u32 best = min((u32)(uo * uo), (u32)min((u32)bestpk[0], (u32)bestpk[1]));
  if (__any(uo > 8)) {                         // rare exact fallback, dy 8..32
    const int c = 2 * e + P;
    #pragma unroll 1
    for (int dy = 8; dy <= HALO; ++dy) {
      int rd = c + dy, ru = c - dy;
      u32 dd = cb[rd >> 1], du = cb[ru >> 1];
      int ud = (int)((dd >> ((rd & 1) * 16)) & 0xffffu);
      int uu = (int)((du >> ((ru & 1) * 16)) & 0xffffu);
      int q = dy * dy;
      best = min(best, (u32)(ud * ud + q));
      best = min(best, (u32)(uu * uu + q));
    }
  }
  float D = sqrtf((float)best);                // = posdis+negdis at this pixel
  float v = *ip;
  float p = 1.0f / (1.0f + __expf(-v));
  aP += p;
  if (fg) { aTP += p; aC += 1; aS -= p * D; } else { aS += p * D; }
  aM = max(aM, best);
}

__global__ void __launch_bounds__(256) k_env(const char* __restrict__ d1b,
                                             const float* __restrict__ inp,
                                             float* __restrict__ partS,
                                             u32* __restrict__ partM,
                                             float* __restrict__ partP,
                                             float* __restrict__ partTP,
                                             int* __restrict__ partT) {
  __shared__ u32 posT[64 * CDW];               // column-major u16, 2 rows/dword
  __shared__ u32 negT[64 * CDW];
  const int tid = threadIdx.x;
  const int cg = blockIdx.x, xt = blockIdx.y, b = blockIdx.z;
  const int w0 = cg * 64, x0 = xt * XT;

  // transposed two-class staging: 512 units = (row-pair r2) x (col-group c8)
  #pragma unroll
  for (int u = 0; u < 2; ++u) {
    int idx = tid + u * 256;
    int r2 = idx >> 3, c8 = idx & 7;
    int g0 = x0 - HALO + 2 * r2;
    const char* base = d1b + ((size_t)(b * HH)) * WW + w0 + c8 * 8;
    uint2 A = make_uint2(0, 0), Bv = make_uint2(0, 0);
    bool ok0 = (unsigned)g0 < (unsigned)HH;
    bool ok1 = (unsigned)(g0 + 1) < (unsigned)HH;
    if (ok0) A  = *(const uint2*)(base + (size_t)g0 * WW);
    if (ok1) Bv = *(const uint2*)(base + (size_t)(g0 + 1) * WW);
    u32 aw[2] = {A.x, A.y}, bw[2] = {Bv.x, Bv.y};
    #pragma unroll
    for (int j = 0; j < 8; ++j) {
      int sa = ((int)(aw[j >> 2] << ((3 - (j & 3)) * 8))) >> 24;  // sext byte
      int sb = ((int)(bw[j >> 2] << ((3 - (j & 3)) * 8))) >> 24;
      int vpa = ok0 ? max(sa, 0) : 127, vna = ok0 ? max(-sa, 0) : 127;
      int vpb = ok1 ? max(sb, 0) : 127, vnb = ok1 ? max(-sb, 0) : 127;
      int col = c8 * 8 + j;
      posT[col * CDW + r2] = (u32)vpa | ((u32)vpb << 16);
      negT[col * CDW + r2] = (u32)vna | ((u32)vnb << 16);
    }
  }
  __syncthreads();

  const int wv = tid >> 6, lane = tid & 63;
  const u32* pc = posT + lane * CDW;
  const u32* nc = negT + lane * CDW;
  const float* ip0 = inp + ((size_t)(b * HH + x0 + wv * 16)) * WW + w0 + lane;
  float aP = 0.f, aTP = 0.f, aS = 0.f;
  u32 aM = 0; int aC = 0;

  #pragma unroll 1
  for (int k2 = 0; k2 < 8; ++k2) {
    const int e = (HALO + wv * 16) / 2 + k2;   // own row-pair dword index
    row_body<0>(e, pc, nc, ip0 + (size_t)(2 * k2) * WW,     aP, aTP, aS, aM, aC);
    row_body<1>(e, pc, nc, ip0 + (size_t)(2 * k2 + 1) * WW, aP, aTP, aS, aM, aC);
  }

  // wave reduce
  #pragma unroll
  for (int off = 32; off >= 1; off >>= 1) {
    aP  += __shfl_xor(aP, off);
    aTP += __shfl_xor(aTP, off);
    aS  += __shfl_xor(aS, off);
    aC  += __shfl_xor(aC, off);
    aM = max(aM, (u32)__shfl_xor((int)aM, off));
  }
  __shared__ float rP[4], rTP[4], rS[4];
  __shared__ u32 rM[4]; __shared__ int rC[4];
  if (lane == 0) { rP[wv] = aP; rTP[wv] = aTP; rS[wv] = aS; rM[wv] = aM; rC[wv] = aC; }
  __syncthreads();
  if (tid == 0) {
    int part = (b * 8 + xt) * 8 + cg;
    partP[part]  = rP[0] + rP[1] + rP[2] + rP[3];
    partTP[part] = rTP[0] + rTP[1] + rTP[2] + rTP[3];
    partS[part]  = rS[0] + rS[1] + rS[2] + rS[3];
    partM[part]  = max(max(rM[0], rM[1]), max(rM[2], rM[3]));
    partT[part]  = rC[0] + rC[1] + rC[2] + rC[3];
  }
}

// ---------------- Kernel C: finalize scalar loss -----------------------------
__global__ void __launch_bounds__(256) k_final(const float* __restrict__ partS,
                                               const u32* __restrict__ partM,
                                               const float* __restrict__ partP,
                                               const float* __restrict__ partTP,
                                               const int* __restrict__ partT,
                                               float* __restrict__ out) {
  const int t = threadIdx.x;
  const int img = t >> 4, j = t & 15;          // 16 threads per image
  float s = 0.f, p = 0.f, tp = 0.f; int tc = 0; u32 m2 = 0;
  #pragma unroll
  for (int q = 0; q < 4; ++q) {
    int e = img * 64 + j + q * 16;
    s += partS[e]; p += partP[e]; tp += partTP[e]; tc += partT[e];
    m2 = max(m2, partM[e]);
  }
  #pragma unroll
  for (int off = 8; off >= 1; off >>= 1) {
    s  += __shfl_xor(s, off);
    p  += __shfl_xor(p, off);
    tp += __shfl_xor(tp, off);
    tc += __shfl_xor(tc, off);
    m2 = max(m2, (u32)__shfl_xor((int)m2, off));
  }
  __shared__ float shC[16], shP[16], shTP[16]; __shared__ int shT[16];
  if (j == 0) {
    float bmax = sqrtf((float)m2);
    shC[img] = (tc > 0) ? (s / (bmax + 1e-8f)) : 0.0f;   // anypos guard
    shP[img] = p; shTP[img] = tp; shT[img] = tc;
  }
  __syncthreads();
  if (t == 0) {
    float sumP = 0.f, TP = 0.f, sumT = 0.f, bl = 0.f;
    for (int i = 0; i < 16; ++i) { sumP += shP[i]; TP += shTP[i]; sumT += (float)shT[i]; bl += shC[i]; }
    float FP = sumP - TP, FN = sumT - TP;
    float tv = (TP + 1.0f) / (TP + 0.3f * FP + 0.7f * FN + 1.0f);
    float ft = powf(1.0f - tv, 1.33f);
    float dice = (2.0f * TP + 1.0f) / (sumP + sumT + 1.0f);
    float dl = 1.0f - dice;
    float blm = bl / (float)NPIX;
    if (isnan(ft)) ft = 0.0f;
    if (isnan(dl)) dl = 0.0f;
    if (isnan(blm)) blm = 0.0f;
    out[0] = 0.5f * ft + 0.3f * dl + 0.2f * blm;
  }
}

extern "C" void kernel_launch(void* const* d_in, const int* in_sizes, int n_in,
                              void* d_out, int out_size, void* d_ws, size_t ws_size,
                              hipStream_t stream) {
  const float* inp = (const float*)d_in[0];
  const int* tg = (const int*)d_in[1];
  float* out = (float*)d_out;
  char* ws = (char*)d_ws;
  char* d1b = (char*)(ws + D1_OFF);
  float* partS  = (float*)(ws + PART_OFF);
  u32*   partM  = (u32*)(ws + PART_OFF + 4096);
  float* partP  = (float*)(ws + PART_OFF + 8192);
  float* partTP = (float*)(ws + PART_OFF + 12288);
  int*   partT  = (int*)(ws + PART_OFF + 16384);

  hipLaunchKernelGGL(k_rows, dim3(BB * HH / 4), dim3(256), 0, stream, tg, d1b);
  hipLaunchKernelGGL(k_env, dim3(WW / 64, HH / XT, BB), dim3(256), 0, stream,
                     d1b, inp, partS, partM, partP, partTP, partT);
  hipLaunchKernelGGL(k_final, dim3(1), dim3(256), 0, stream,
                     partS, partM, partP, partTP, partT, out);
}